// Round 1
// baseline (770.728 us; speedup 1.0000x reference)
//
#include <hip/hip_runtime.h>

// Problem constants
#define Bn 131072
#define Dn 256
#define Hn 256
#define Cn 8

// ---------------------------------------------------------------------------
// Phase A: h = relu(x@W1 + b1); logits = h@W2 + b2; softmax; routing.
// Writes: out_h (default h), out_logits (default logits), depths,
//         per-expert row lists + counts in workspace.
// Block: 256 threads, tile = 64 rows x 256 cols, thread tile 4x16.
// ---------------------------------------------------------------------------
__global__ __launch_bounds__(256)
void root_kernel(const float* __restrict__ x, const float* __restrict__ W1,
                 const float* __restrict__ b1, const float* __restrict__ W2,
                 const float* __restrict__ b2, const float* __restrict__ tau,
                 float* __restrict__ out_logits, float* __restrict__ out_h,
                 float* __restrict__ out_depth, int* __restrict__ cnt,
                 int* __restrict__ lists)
{
    __shared__ float sAT[32][68];     // transposed x tile [k][row], pad 64->68
    __shared__ float sB[32][256];     // W1 tile [k][n]
    __shared__ float sW2[Hn * Cn];    // W2 staged whole (256x8)
    __shared__ float sRed[64][8];     // reduced logits per row
    __shared__ int   sCnt[8], sBase[8], sBest[64], sSlot[64];

    const int t  = threadIdx.x;
    const int tx = t & 15;            // 16 col groups
    const int ty = t >> 4;            // 16 row groups (4 rows each)
    const long r0 = (long)blockIdx.x * 64;

    // stage W2 (2048 floats = 512 float4)
    {
        const float4* g = (const float4*)W2;
        float4* s = (float4*)sW2;
        s[t]       = g[t];
        s[t + 256] = g[t + 256];
    }
    if (t < 8) sCnt[t] = 0;

    float acc[4][16];
#pragma unroll
    for (int r = 0; r < 4; r++)
#pragma unroll
        for (int i = 0; i < 16; i++) acc[r][i] = 0.0f;

    for (int k0 = 0; k0 < Dn; k0 += 32) {
        __syncthreads();
        // load x tile: 64 rows x 32 k (512 float4, 2 per thread), store transposed
#pragma unroll
        for (int j = 0; j < 2; j++) {
            const int f   = j * 256 + t;
            const int row = f >> 3;          // 0..63
            const int kv  = f & 7;           // float4 index within 32-k chunk
            const float4 v = ((const float4*)x)[(r0 + row) * 64 + (k0 >> 2) + kv];
            sAT[kv * 4 + 0][row] = v.x;
            sAT[kv * 4 + 1][row] = v.y;
            sAT[kv * 4 + 2][row] = v.z;
            sAT[kv * 4 + 3][row] = v.w;
        }
        // load W1 tile: 32 k x 256 n (2048 float4, 8 per thread)
#pragma unroll
        for (int j = 0; j < 8; j++) {
            const int f  = j * 256 + t;      // float4 index in tile
            const int kr = f >> 6;           // 0..31
            const int n4 = f & 63;           // 0..63
            ((float4*)&sB[kr][0])[n4] =
                ((const float4*)W1)[(long)(k0 + kr) * 64 + n4];
        }
        __syncthreads();

#pragma unroll 8
        for (int kk = 0; kk < 32; kk++) {
            const float4 a4 = *(const float4*)&sAT[kk][ty * 4];
            const float av[4] = {a4.x, a4.y, a4.z, a4.w};
#pragma unroll
            for (int cb = 0; cb < 4; cb++) {
                const float4 b4 = *(const float4*)&sB[kk][cb * 64 + tx * 4];
                const float bv[4] = {b4.x, b4.y, b4.z, b4.w};
#pragma unroll
                for (int r = 0; r < 4; r++)
#pragma unroll
                    for (int i = 0; i < 4; i++)
                        acc[r][cb * 4 + i] += av[r] * bv[i];
            }
        }
    }

    // ---- epilogue: bias + relu, store h, partial logits ----
    float p[4][8];
#pragma unroll
    for (int r = 0; r < 4; r++)
#pragma unroll
        for (int c = 0; c < 8; c++) p[r][c] = 0.0f;

#pragma unroll
    for (int cb = 0; cb < 4; cb++) {
        const int col0 = cb * 64 + tx * 4;
        const float4 bb = *(const float4*)&b1[col0];
        float4 hv[4];
#pragma unroll
        for (int r = 0; r < 4; r++) {
            float4 h4;
            h4.x = fmaxf(acc[r][cb * 4 + 0] + bb.x, 0.0f);
            h4.y = fmaxf(acc[r][cb * 4 + 1] + bb.y, 0.0f);
            h4.z = fmaxf(acc[r][cb * 4 + 2] + bb.z, 0.0f);
            h4.w = fmaxf(acc[r][cb * 4 + 3] + bb.w, 0.0f);
            hv[r] = h4;
            ((float4*)out_h)[(r0 + ty * 4 + r) * 64 + (col0 >> 2)] = h4;
        }
#pragma unroll
        for (int i = 0; i < 4; i++) {
            const float4 wA = *(const float4*)&sW2[(col0 + i) * 8];
            const float4 wB = *(const float4*)&sW2[(col0 + i) * 8 + 4];
#pragma unroll
            for (int r = 0; r < 4; r++) {
                const float hval = (i == 0) ? hv[r].x : (i == 1) ? hv[r].y
                                 : (i == 2) ? hv[r].z : hv[r].w;
                p[r][0] += hval * wA.x; p[r][1] += hval * wA.y;
                p[r][2] += hval * wA.z; p[r][3] += hval * wA.w;
                p[r][4] += hval * wB.x; p[r][5] += hval * wB.y;
                p[r][6] += hval * wB.z; p[r][7] += hval * wB.w;
            }
        }
    }

    // butterfly-reduce partial logits across the 16 tx lanes of each row group
#pragma unroll
    for (int r = 0; r < 4; r++)
#pragma unroll
        for (int c = 0; c < 8; c++) {
            float v = p[r][c];
            v += __shfl_xor(v, 8, 16);
            v += __shfl_xor(v, 4, 16);
            v += __shfl_xor(v, 2, 16);
            v += __shfl_xor(v, 1, 16);
            if (tx == 0) sRed[ty * 4 + r][c] = v;
        }
    __syncthreads();

    // ---- routing: one thread per row ----
    if (t < 64) {
        const long row = r0 + t;
        float l[8];
        float mx = -1e30f;
#pragma unroll
        for (int c = 0; c < 8; c++) {
            l[c] = sRed[t][c] + b2[c];
            mx = fmaxf(mx, l[c]);
        }
        float e[8], s = 0.0f;
#pragma unroll
        for (int c = 0; c < 8; c++) { e[c] = expf(l[c] - mx); s += e[c]; }
        const float inv = 1.0f / s;
        int best = 0; float bp = -1.0f;
#pragma unroll
        for (int c = 0; c < 8; c++) {
            const float pr = e[c] * inv;
            const float m  = (pr >= tau[c]) ? pr : -1.0f;
            if (m > bp) { bp = m; best = c; }   // strict > keeps first max (jnp.argmax)
        }
        const bool routed = (bp >= 0.0f);
        float4* lo = (float4*)&out_logits[row * 8];
        lo[0] = make_float4(l[0], l[1], l[2], l[3]);
        lo[1] = make_float4(l[4], l[5], l[6], l[7]);
        out_depth[row] = routed ? 1.0f : 0.0f;
        if (routed) {
            sSlot[t] = atomicAdd(&sCnt[best], 1);
            sBest[t] = best;
        } else {
            sBest[t] = -1;
        }
    }
    __syncthreads();
    if (t < 8) sBase[t] = sCnt[t] ? atomicAdd(&cnt[t], sCnt[t]) : 0;
    __syncthreads();
    if (t < 64 && sBest[t] >= 0) {
        const int e = sBest[t];
        lists[(long)e * Bn + sBase[e] + sSlot[t]] = (int)(r0 + t);
    }
}

// ---------------------------------------------------------------------------
// Phase B: for routed rows of expert e: h_c = relu(h@Wc1[e]+bc1[e]),
// l_c = h_c@Wc2[e]+bc2[e]; overwrite out_h/out_logits rows.
// Grid: (B/64 tiles, 8 experts); blocks beyond count[e] exit immediately.
// ---------------------------------------------------------------------------
__global__ __launch_bounds__(256)
void expert_kernel(const float* __restrict__ Wc1, const float* __restrict__ bc1,
                   const float* __restrict__ Wc2, const float* __restrict__ bc2,
                   float* __restrict__ out_logits, float* __restrict__ out_h,
                   const int* __restrict__ cnt, const int* __restrict__ lists)
{
    const int e = blockIdx.y;
    const int n = cnt[e];
    const int tile0 = blockIdx.x * 64;
    if (tile0 >= n) return;
    const int nrows = min(64, n - tile0);

    __shared__ float sAT[32][68];
    __shared__ float sB[32][256];
    __shared__ float sW2c[Hn * Cn];
    __shared__ float sRed[64][8];
    __shared__ int   sRidx[64];

    const int t  = threadIdx.x;
    const int tx = t & 15;
    const int ty = t >> 4;

    if (t < 64) sRidx[t] = lists[(long)e * Bn + tile0 + min(t, nrows - 1)];
    {
        const float4* g = (const float4*)(Wc2 + (long)e * Hn * Cn);
        float4* s = (float4*)sW2c;
        s[t]       = g[t];
        s[t + 256] = g[t + 256];
    }
    const float* W = Wc1 + (long)e * Hn * Hn;

    float acc[4][16];
#pragma unroll
    for (int r = 0; r < 4; r++)
#pragma unroll
        for (int i = 0; i < 16; i++) acc[r][i] = 0.0f;

    for (int k0 = 0; k0 < Hn; k0 += 32) {
        __syncthreads();
        // gather h rows (64 x 32 floats)
#pragma unroll
        for (int j = 0; j < 2; j++) {
            const int f   = j * 256 + t;
            const int row = f >> 3;
            const int kv  = f & 7;
            const float4 v =
                ((const float4*)out_h)[(long)sRidx[row] * 64 + (k0 >> 2) + kv];
            sAT[kv * 4 + 0][row] = v.x;
            sAT[kv * 4 + 1][row] = v.y;
            sAT[kv * 4 + 2][row] = v.z;
            sAT[kv * 4 + 3][row] = v.w;
        }
#pragma unroll
        for (int j = 0; j < 8; j++) {
            const int f  = j * 256 + t;
            const int kr = f >> 6;
            const int n4 = f & 63;
            ((float4*)&sB[kr][0])[n4] =
                ((const float4*)W)[(long)(k0 + kr) * 64 + n4];
        }
        __syncthreads();

#pragma unroll 8
        for (int kk = 0; kk < 32; kk++) {
            const float4 a4 = *(const float4*)&sAT[kk][ty * 4];
            const float av[4] = {a4.x, a4.y, a4.z, a4.w};
#pragma unroll
            for (int cb = 0; cb < 4; cb++) {
                const float4 b4 = *(const float4*)&sB[kk][cb * 64 + tx * 4];
                const float bv[4] = {b4.x, b4.y, b4.z, b4.w};
#pragma unroll
                for (int r = 0; r < 4; r++)
#pragma unroll
                    for (int i = 0; i < 4; i++)
                        acc[r][cb * 4 + i] += av[r] * bv[i];
            }
        }
    }

    // epilogue: bias + relu, store h_c (guarded), partial l_c
    const float* bc1e = bc1 + (long)e * Hn;
    float p[4][8];
#pragma unroll
    for (int r = 0; r < 4; r++)
#pragma unroll
        for (int c = 0; c < 8; c++) p[r][c] = 0.0f;

#pragma unroll
    for (int cb = 0; cb < 4; cb++) {
        const int col0 = cb * 64 + tx * 4;
        const float4 bb = *(const float4*)&bc1e[col0];
        float4 hv[4];
#pragma unroll
        for (int r = 0; r < 4; r++) {
            float4 h4;
            h4.x = fmaxf(acc[r][cb * 4 + 0] + bb.x, 0.0f);
            h4.y = fmaxf(acc[r][cb * 4 + 1] + bb.y, 0.0f);
            h4.z = fmaxf(acc[r][cb * 4 + 2] + bb.z, 0.0f);
            h4.w = fmaxf(acc[r][cb * 4 + 3] + bb.w, 0.0f);
            hv[r] = h4;
            if (ty * 4 + r < nrows)
                ((float4*)out_h)[(long)sRidx[ty * 4 + r] * 64 + (col0 >> 2)] = h4;
        }
#pragma unroll
        for (int i = 0; i < 4; i++) {
            const float4 wA = *(const float4*)&sW2c[(col0 + i) * 8];
            const float4 wB = *(const float4*)&sW2c[(col0 + i) * 8 + 4];
#pragma unroll
            for (int r = 0; r < 4; r++) {
                const float hval = (i == 0) ? hv[r].x : (i == 1) ? hv[r].y
                                 : (i == 2) ? hv[r].z : hv[r].w;
                p[r][0] += hval * wA.x; p[r][1] += hval * wA.y;
                p[r][2] += hval * wA.z; p[r][3] += hval * wA.w;
                p[r][4] += hval * wB.x; p[r][5] += hval * wB.y;
                p[r][6] += hval * wB.z; p[r][7] += hval * wB.w;
            }
        }
    }

#pragma unroll
    for (int r = 0; r < 4; r++)
#pragma unroll
        for (int c = 0; c < 8; c++) {
            float v = p[r][c];
            v += __shfl_xor(v, 8, 16);
            v += __shfl_xor(v, 4, 16);
            v += __shfl_xor(v, 2, 16);
            v += __shfl_xor(v, 1, 16);
            if (tx == 0) sRed[ty * 4 + r][c] = v;
        }
    __syncthreads();

    if (t < nrows) {
        const long row = sRidx[t];
        const float* bc2e = bc2 + (long)e * Cn;
        float4* lo = (float4*)&out_logits[row * 8];
        lo[0] = make_float4(sRed[t][0] + bc2e[0], sRed[t][1] + bc2e[1],
                            sRed[t][2] + bc2e[2], sRed[t][3] + bc2e[3]);
        lo[1] = make_float4(sRed[t][4] + bc2e[4], sRed[t][5] + bc2e[5],
                            sRed[t][6] + bc2e[6], sRed[t][7] + bc2e[7]);
    }
}

extern "C" void kernel_launch(void* const* d_in, const int* in_sizes, int n_in,
                              void* d_out, int out_size, void* d_ws, size_t ws_size,
                              hipStream_t stream)
{
    const float* x   = (const float*)d_in[0];
    const float* W1  = (const float*)d_in[1];
    const float* b1  = (const float*)d_in[2];
    const float* W2  = (const float*)d_in[3];
    const float* b2  = (const float*)d_in[4];
    const float* Wc1 = (const float*)d_in[5];
    const float* bc1 = (const float*)d_in[6];
    const float* Wc2 = (const float*)d_in[7];
    const float* bc2 = (const float*)d_in[8];
    const float* tau = (const float*)d_in[9];

    float* out_logits = (float*)d_out;                       // [B, 8]
    float* out_h      = out_logits + (long)Bn * Cn;          // [B, 256]
    float* out_depth  = out_h + (long)Bn * Hn;               // [B]

    int* cnt   = (int*)d_ws;                                 // 8 counters
    int* lists = (int*)((char*)d_ws + 128);                  // 8 x B row indices

    hipMemsetAsync(d_ws, 0, 128, stream);

    root_kernel<<<dim3(Bn / 64), 256, 0, stream>>>(
        x, W1, b1, W2, b2, tau, out_logits, out_h, out_depth, cnt, lists);

    expert_kernel<<<dim3(Bn / 64, 8), 256, 0, stream>>>(
        Wc1, bc1, Wc2, bc2, out_logits, out_h, cnt, lists);
}

// Round 3
// 665.475 us; speedup vs baseline: 1.1582x; 1.1582x over previous
//
#include <hip/hip_runtime.h>

// Problem constants
#define Bn 131072
#define Dn 256
#define Hn 256
#define Cn 8

typedef __attribute__((ext_vector_type(4))) float f32x4;
typedef __attribute__((ext_vector_type(8))) __bf16 bf16x8;

#define LDA 40   // LDS row stride in bf16 units (80B): 2-way bank aliasing = free

// ---- bf16 split helpers (round-to-nearest at every stage) ----
__device__ inline unsigned short rtn_bf16(float v) {
    unsigned int u = __float_as_uint(v);
    unsigned int r = u + 0x7fffu + ((u >> 16) & 1u);
    return (unsigned short)(r >> 16);
}
__device__ inline float bf16_to_f(unsigned short h) {
    return __uint_as_float((unsigned int)h << 16);
}
__device__ inline void split3(float v, unsigned short& a0, unsigned short& a1,
                              unsigned short& a2) {
    a0 = rtn_bf16(v); float r = v - bf16_to_f(a0);
    a1 = rtn_bf16(r); r -= bf16_to_f(a1);
    a2 = rtn_bf16(r);
}
__device__ inline void split2(float v, unsigned short& a0, unsigned short& a1) {
    a0 = rtn_bf16(v);
    a1 = rtn_bf16(v - bf16_to_f(a0));
}

// ---------------------------------------------------------------------------
// Prep: W1[k][n] -> 3 bf16 splits transposed [n][k]; Wc1[e][k][n] -> 2 splits.
// ---------------------------------------------------------------------------
__global__ __launch_bounds__(256)
void prep_kernel(const float* __restrict__ W1, const float* __restrict__ Wc1,
                 unsigned short* __restrict__ W1t0, unsigned short* __restrict__ W1t1,
                 unsigned short* __restrict__ W1t2,
                 unsigned short* __restrict__ Wc1t0, unsigned short* __restrict__ Wc1t1)
{
    const int idx = blockIdx.x * 256 + threadIdx.x;
    if (idx < 65536) {
        const int n = idx >> 8, k = idx & 255;
        unsigned short a0, a1, a2;
        split3(W1[k * 256 + n], a0, a1, a2);
        W1t0[idx] = a0; W1t1[idx] = a1; W1t2[idx] = a2;
    } else {
        const int j = idx - 65536;            // 0 .. 8*65536-1
        const int e = j >> 16, rem = j & 65535;
        const int n = rem >> 8, k = rem & 255;
        unsigned short a0, a1;
        split2(Wc1[(e << 16) + k * 256 + n], a0, a1);
        const int o = (e << 16) + n * 256 + k;
        Wc1t0[o] = a0; Wc1t1[o] = a1;
    }
}

// ---------------------------------------------------------------------------
// Phase A: h = relu(x@W1+b1) via 3-split/6-product bf16 MFMA (fp32-accurate);
// logits = h@W2+b2 fp32; softmax + routing; per-expert row lists.
// Block: 512 threads (8 waves), tile 64 rows x 256 cols.
// Wave w: cols [w*32, w*32+32), 4 m-tiles x 2 n-tiles of 16x16.
// B fragments load directly from global (L2-resident weight splits).
// ---------------------------------------------------------------------------
__global__ __launch_bounds__(512, 4)
void root_kernel(const float* __restrict__ x,
                 const unsigned short* __restrict__ Wt0,
                 const unsigned short* __restrict__ Wt1,
                 const unsigned short* __restrict__ Wt2,
                 const float* __restrict__ b1, const float* __restrict__ W2,
                 const float* __restrict__ b2, const float* __restrict__ tau,
                 float* __restrict__ out_logits, float* __restrict__ out_h,
                 float* __restrict__ out_depth, int* __restrict__ cnt,
                 int* __restrict__ lists)
{
    __shared__ unsigned short sA0[64 * LDA], sA1[64 * LDA], sA2[64 * LDA]; // 5KB ea
    __shared__ float sW2[Hn * Cn];                                         // 8KB
    __shared__ float sP[64][8];                                            // 2KB
    __shared__ int   sCnt[8], sBase[8], sBest[64], sSlot[64];

    const int t    = threadIdx.x;
    const int lane = t & 63;
    const int w    = t >> 6;          // wave 0..7
    const int tx   = lane & 15;
    const int q    = lane >> 4;       // quad 0..3
    const long r0  = (long)blockIdx.x * 64;

    ((float4*)sW2)[t] = ((const float4*)W2)[t];
    if (t < 8) sCnt[t] = 0;
    ((float*)sP)[t] = 0.0f;

    const int colA = w * 32 + tx;
    const int colB = colA + 16;
    const unsigned short* bA0 = Wt0 + colA * 256 + q * 8;
    const unsigned short* bA1 = Wt1 + colA * 256 + q * 8;
    const unsigned short* bA2 = Wt2 + colA * 256 + q * 8;
    const unsigned short* bB0 = Wt0 + colB * 256 + q * 8;
    const unsigned short* bB1 = Wt1 + colB * 256 + q * 8;
    const unsigned short* bB2 = Wt2 + colB * 256 + q * 8;

    f32x4 acc[4][2];
#pragma unroll
    for (int mt = 0; mt < 4; mt++)
#pragma unroll
        for (int nt = 0; nt < 2; nt++) acc[mt][nt] = (f32x4)0.0f;

    // prefetch first x chunk: 64 rows x 32 k = 512 float4, one per thread
    const int arow = t >> 3, ak4 = t & 7;
    float4 xv = ((const float4*)x)[(r0 + arow) * 64 + ak4];

    for (int k0 = 0; k0 < Dn; k0 += 32) {
        __syncthreads();
        {
            unsigned short h0[4], h1[4], h2[4];
            split3(xv.x, h0[0], h1[0], h2[0]);
            split3(xv.y, h0[1], h1[1], h2[1]);
            split3(xv.z, h0[2], h1[2], h2[2]);
            split3(xv.w, h0[3], h1[3], h2[3]);
            *(ushort4*)&sA0[arow * LDA + ak4 * 4] = make_ushort4(h0[0], h0[1], h0[2], h0[3]);
            *(ushort4*)&sA1[arow * LDA + ak4 * 4] = make_ushort4(h1[0], h1[1], h1[2], h1[3]);
            *(ushort4*)&sA2[arow * LDA + ak4 * 4] = make_ushort4(h2[0], h2[1], h2[2], h2[3]);
        }
        __syncthreads();
        if (k0 < Dn - 32)
            xv = ((const float4*)x)[(r0 + arow) * 64 + ((k0 + 32) >> 2) + ak4];

        // B fragments for this k-chunk (global, L1/L2-hot)
        const bf16x8 B0s0 = *(const bf16x8*)(bA0 + k0);
        const bf16x8 B0s1 = *(const bf16x8*)(bA1 + k0);
        const bf16x8 B0s2 = *(const bf16x8*)(bA2 + k0);
        const bf16x8 B1s0 = *(const bf16x8*)(bB0 + k0);
        const bf16x8 B1s1 = *(const bf16x8*)(bB1 + k0);
        const bf16x8 B1s2 = *(const bf16x8*)(bB2 + k0);

#pragma unroll
        for (int mt = 0; mt < 4; mt++) {
            const bf16x8 A0 = *(const bf16x8*)&sA0[(mt * 16 + tx) * LDA + q * 8];
            const bf16x8 A1 = *(const bf16x8*)&sA1[(mt * 16 + tx) * LDA + q * 8];
            const bf16x8 A2 = *(const bf16x8*)&sA2[(mt * 16 + tx) * LDA + q * 8];
            acc[mt][0] = __builtin_amdgcn_mfma_f32_16x16x32_bf16(A0, B0s0, acc[mt][0], 0, 0, 0);
            acc[mt][0] = __builtin_amdgcn_mfma_f32_16x16x32_bf16(A0, B0s1, acc[mt][0], 0, 0, 0);
            acc[mt][0] = __builtin_amdgcn_mfma_f32_16x16x32_bf16(A1, B0s0, acc[mt][0], 0, 0, 0);
            acc[mt][0] = __builtin_amdgcn_mfma_f32_16x16x32_bf16(A1, B0s1, acc[mt][0], 0, 0, 0);
            acc[mt][0] = __builtin_amdgcn_mfma_f32_16x16x32_bf16(A0, B0s2, acc[mt][0], 0, 0, 0);
            acc[mt][0] = __builtin_amdgcn_mfma_f32_16x16x32_bf16(A2, B0s0, acc[mt][0], 0, 0, 0);
            acc[mt][1] = __builtin_amdgcn_mfma_f32_16x16x32_bf16(A0, B1s0, acc[mt][1], 0, 0, 0);
            acc[mt][1] = __builtin_amdgcn_mfma_f32_16x16x32_bf16(A0, B1s1, acc[mt][1], 0, 0, 0);
            acc[mt][1] = __builtin_amdgcn_mfma_f32_16x16x32_bf16(A1, B1s0, acc[mt][1], 0, 0, 0);
            acc[mt][1] = __builtin_amdgcn_mfma_f32_16x16x32_bf16(A1, B1s1, acc[mt][1], 0, 0, 0);
            acc[mt][1] = __builtin_amdgcn_mfma_f32_16x16x32_bf16(A0, B1s2, acc[mt][1], 0, 0, 0);
            acc[mt][1] = __builtin_amdgcn_mfma_f32_16x16x32_bf16(A2, B1s0, acc[mt][1], 0, 0, 0);
        }
    }

    // ---- epilogue: bias+relu, store h, fp32 head partials ----
    const float b1c0 = b1[colA], b1c1 = b1[colB];
    float w20[8], w21[8];
#pragma unroll
    for (int c = 0; c < 8; c++) { w20[c] = sW2[colA * 8 + c]; w21[c] = sW2[colB * 8 + c]; }

#pragma unroll
    for (int mt = 0; mt < 4; mt++) {
        float pm[4][8];
#pragma unroll
        for (int reg = 0; reg < 4; reg++) {
            const float h0 = fmaxf(acc[mt][0][reg] + b1c0, 0.0f);
            const float h1 = fmaxf(acc[mt][1][reg] + b1c1, 0.0f);
            const int row = mt * 16 + q * 4 + reg;
            out_h[(r0 + row) * 256 + colA] = h0;
            out_h[(r0 + row) * 256 + colB] = h1;
#pragma unroll
            for (int c = 0; c < 8; c++)
                pm[reg][c] = h0 * w20[c] + h1 * w21[c];
        }
#pragma unroll
        for (int reg = 0; reg < 4; reg++)
#pragma unroll
            for (int c = 0; c < 8; c++) {
                float v = pm[reg][c];
                v += __shfl_xor(v, 1, 16);
                v += __shfl_xor(v, 2, 16);
                v += __shfl_xor(v, 4, 16);
                v += __shfl_xor(v, 8, 16);
                if (tx == 0) atomicAdd(&sP[mt * 16 + q * 4 + reg][c], v);
            }
    }
    __syncthreads();

    // ---- routing: one thread per row ----
    if (t < 64) {
        const long row = r0 + t;
        float l[8];
        float mx = -1e30f;
#pragma unroll
        for (int c = 0; c < 8; c++) {
            l[c] = sP[t][c] + b2[c];
            mx = fmaxf(mx, l[c]);
        }
        float e[8], s = 0.0f;
#pragma unroll
        for (int c = 0; c < 8; c++) { e[c] = expf(l[c] - mx); s += e[c]; }
        const float inv = 1.0f / s;
        int best = 0; float bp = -1.0f;
#pragma unroll
        for (int c = 0; c < 8; c++) {
            const float pr = e[c] * inv;
            const float m  = (pr >= tau[c]) ? pr : -1.0f;
            if (m > bp) { bp = m; best = c; }   // strict > == first max (jnp.argmax)
        }
        const bool routed = (bp >= 0.0f);
        float4* lo4 = (float4*)&out_logits[row * 8];
        lo4[0] = make_float4(l[0], l[1], l[2], l[3]);
        lo4[1] = make_float4(l[4], l[5], l[6], l[7]);
        out_depth[row] = routed ? 1.0f : 0.0f;
        if (routed) {
            sSlot[t] = atomicAdd(&sCnt[best], 1);
            sBest[t] = best;
        } else {
            sBest[t] = -1;
        }
    }
    __syncthreads();
    if (t < 8) sBase[t] = sCnt[t] ? atomicAdd(&cnt[t], sCnt[t]) : 0;
    __syncthreads();
    if (t < 64 && sBest[t] >= 0) {
        const int e = sBest[t];
        lists[(long)e * Bn + sBase[e] + sSlot[t]] = (int)(r0 + t);
    }
}

// ---------------------------------------------------------------------------
// Phase B: routed rows of expert e: h_c = relu(h@Wc1[e]+bc1[e]) via
// 2-split/3-product MFMA; l_c = h_c@Wc2[e]+bc2[e] fp32; overwrite rows.
// ---------------------------------------------------------------------------
__global__ __launch_bounds__(512, 4)
void expert_kernel(const unsigned short* __restrict__ Wc1t0,
                   const unsigned short* __restrict__ Wc1t1,
                   const float* __restrict__ bc1,
                   const float* __restrict__ Wc2, const float* __restrict__ bc2,
                   float* __restrict__ out_logits, float* __restrict__ out_h,
                   const int* __restrict__ cnt, const int* __restrict__ lists)
{
    const int e = blockIdx.y;
    const int n = cnt[e];
    const int tile0 = blockIdx.x * 64;
    if (tile0 >= n) return;
    const int nrows = min(64, n - tile0);

    __shared__ unsigned short sA0[64 * LDA], sA1[64 * LDA];
    __shared__ float sW2c[Hn * Cn];
    __shared__ float sP[64][8];
    __shared__ int   sRidx[64];

    const int t    = threadIdx.x;
    const int lane = t & 63;
    const int w    = t >> 6;
    const int tx   = lane & 15;
    const int q    = lane >> 4;

    if (t < 64) sRidx[t] = lists[(long)e * Bn + tile0 + min(t, nrows - 1)];
    ((float4*)sW2c)[t] = ((const float4*)(Wc2 + (long)e * Hn * Cn))[t];
    ((float*)sP)[t] = 0.0f;

    const unsigned short* Wh = Wc1t0 + (long)e * 65536;
    const unsigned short* Wl = Wc1t1 + (long)e * 65536;
    const int colA = w * 32 + tx;
    const int colB = colA + 16;
    const unsigned short* bA0 = Wh + colA * 256 + q * 8;
    const unsigned short* bA1 = Wl + colA * 256 + q * 8;
    const unsigned short* bB0 = Wh + colB * 256 + q * 8;
    const unsigned short* bB1 = Wl + colB * 256 + q * 8;

    f32x4 acc[4][2];
#pragma unroll
    for (int mt = 0; mt < 4; mt++)
#pragma unroll
        for (int nt = 0; nt < 2; nt++) acc[mt][nt] = (f32x4)0.0f;

    const int arow = t >> 3, ak4 = t & 7;
    __syncthreads();   // sRidx visible before gather
    float4 xv = ((const float4*)out_h)[(long)sRidx[arow] * 64 + ak4];

    for (int k0 = 0; k0 < Hn; k0 += 32) {
        __syncthreads();
        {
            unsigned short h0[4], h1[4];
            split2(xv.x, h0[0], h1[0]);
            split2(xv.y, h0[1], h1[1]);
            split2(xv.z, h0[2], h1[2]);
            split2(xv.w, h0[3], h1[3]);
            *(ushort4*)&sA0[arow * LDA + ak4 * 4] = make_ushort4(h0[0], h0[1], h0[2], h0[3]);
            *(ushort4*)&sA1[arow * LDA + ak4 * 4] = make_ushort4(h1[0], h1[1], h1[2], h1[3]);
        }
        __syncthreads();
        if (k0 < Hn - 32)
            xv = ((const float4*)out_h)[(long)sRidx[arow] * 64 + ((k0 + 32) >> 2) + ak4];

        const bf16x8 B0s0 = *(const bf16x8*)(bA0 + k0);
        const bf16x8 B0s1 = *(const bf16x8*)(bA1 + k0);
        const bf16x8 B1s0 = *(const bf16x8*)(bB0 + k0);
        const bf16x8 B1s1 = *(const bf16x8*)(bB1 + k0);

#pragma unroll
        for (int mt = 0; mt < 4; mt++) {
            const bf16x8 A0 = *(const bf16x8*)&sA0[(mt * 16 + tx) * LDA + q * 8];
            const bf16x8 A1 = *(const bf16x8*)&sA1[(mt * 16 + tx) * LDA + q * 8];
            acc[mt][0] = __builtin_amdgcn_mfma_f32_16x16x32_bf16(A0, B0s0, acc[mt][0], 0, 0, 0);
            acc[mt][0] = __builtin_amdgcn_mfma_f32_16x16x32_bf16(A0, B0s1, acc[mt][0], 0, 0, 0);
            acc[mt][0] = __builtin_amdgcn_mfma_f32_16x16x32_bf16(A1, B0s0, acc[mt][0], 0, 0, 0);
            acc[mt][1] = __builtin_amdgcn_mfma_f32_16x16x32_bf16(A0, B1s0, acc[mt][1], 0, 0, 0);
            acc[mt][1] = __builtin_amdgcn_mfma_f32_16x16x32_bf16(A0, B1s1, acc[mt][1], 0, 0, 0);
            acc[mt][1] = __builtin_amdgcn_mfma_f32_16x16x32_bf16(A1, B1s0, acc[mt][1], 0, 0, 0);
        }
    }

    const float* bc1e = bc1 + (long)e * Hn;
    const float b1c0 = bc1e[colA], b1c1 = bc1e[colB];
    float w20[8], w21[8];
#pragma unroll
    for (int c = 0; c < 8; c++) { w20[c] = sW2c[colA * 8 + c]; w21[c] = sW2c[colB * 8 + c]; }

#pragma unroll
    for (int mt = 0; mt < 4; mt++) {
        float pm[4][8];
#pragma unroll
        for (int reg = 0; reg < 4; reg++) {
            const float h0 = fmaxf(acc[mt][0][reg] + b1c0, 0.0f);
            const float h1 = fmaxf(acc[mt][1][reg] + b1c1, 0.0f);
            const int row = mt * 16 + q * 4 + reg;
            if (row < nrows) {
                out_h[(long)sRidx[row] * 256 + colA] = h0;
                out_h[(long)sRidx[row] * 256 + colB] = h1;
            }
#pragma unroll
            for (int c = 0; c < 8; c++)
                pm[reg][c] = h0 * w20[c] + h1 * w21[c];
        }
#pragma unroll
        for (int reg = 0; reg < 4; reg++)
#pragma unroll
            for (int c = 0; c < 8; c++) {
                float v = pm[reg][c];
                v += __shfl_xor(v, 1, 16);
                v += __shfl_xor(v, 2, 16);
                v += __shfl_xor(v, 4, 16);
                v += __shfl_xor(v, 8, 16);
                if (tx == 0) atomicAdd(&sP[mt * 16 + q * 4 + reg][c], v);
            }
    }
    __syncthreads();

    if (t < nrows) {
        const long row = sRidx[t];
        const float* bc2e = bc2 + (long)e * Cn;
        float4* lo4 = (float4*)&out_logits[row * 8];
        lo4[0] = make_float4(sP[t][0] + bc2e[0], sP[t][1] + bc2e[1],
                             sP[t][2] + bc2e[2], sP[t][3] + bc2e[3]);
        lo4[1] = make_float4(sP[t][4] + bc2e[4], sP[t][5] + bc2e[5],
                             sP[t][6] + bc2e[6], sP[t][7] + bc2e[7]);
    }
}

extern "C" void kernel_launch(void* const* d_in, const int* in_sizes, int n_in,
                              void* d_out, int out_size, void* d_ws, size_t ws_size,
                              hipStream_t stream)
{
    const float* x   = (const float*)d_in[0];
    const float* W1  = (const float*)d_in[1];
    const float* b1  = (const float*)d_in[2];
    const float* W2  = (const float*)d_in[3];
    const float* b2  = (const float*)d_in[4];
    const float* Wc1 = (const float*)d_in[5];
    const float* bc1 = (const float*)d_in[6];
    const float* Wc2 = (const float*)d_in[7];
    const float* bc2 = (const float*)d_in[8];
    const float* tau = (const float*)d_in[9];

    float* out_logits = (float*)d_out;                       // [B, 8]
    float* out_h      = out_logits + (long)Bn * Cn;          // [B, 256]
    float* out_depth  = out_h + (long)Bn * Hn;               // [B]

    char* wsb = (char*)d_ws;
    int* cnt   = (int*)wsb;                                  // 8 counters
    int* lists = (int*)(wsb + 128);                          // 8 x B ints (4MB)
    unsigned short* W1t0  = (unsigned short*)(wsb + 128 + (size_t)8 * Bn * 4);
    unsigned short* W1t1  = W1t0 + 65536;
    unsigned short* W1t2  = W1t1 + 65536;
    unsigned short* Wc1t0 = W1t2 + 65536;
    unsigned short* Wc1t1 = Wc1t0 + 8 * 65536;

    hipMemsetAsync(d_ws, 0, 128, stream);

    prep_kernel<<<dim3((65536 + 8 * 65536) / 256), 256, 0, stream>>>(
        W1, Wc1, W1t0, W1t1, W1t2, Wc1t0, Wc1t1);

    root_kernel<<<dim3(Bn / 64), 512, 0, stream>>>(
        x, W1t0, W1t1, W1t2, b1, W2, b2, tau, out_logits, out_h, out_depth,
        cnt, lists);

    expert_kernel<<<dim3(Bn / 64, 8), 512, 0, stream>>>(
        Wc1t0, Wc1t1, bc1, Wc2, bc2, out_logits, out_h, cnt, lists);
}

// Round 4
// 657.528 us; speedup vs baseline: 1.1722x; 1.0121x over previous
//
#include <hip/hip_runtime.h>

// Problem constants
#define Bn 131072
#define Dn 256
#define Hn 256
#define Cn 8

typedef __attribute__((ext_vector_type(4))) float f32x4;
typedef __attribute__((ext_vector_type(8))) __bf16 bf16x8;

#define LDA 40   // LDS row stride in bf16 units (80B): 2-way bank aliasing = free

// ---- bf16 split helpers (round-to-nearest at every stage) ----
__device__ inline unsigned short rtn_bf16(float v) {
    unsigned int u = __float_as_uint(v);
    unsigned int r = u + 0x7fffu + ((u >> 16) & 1u);
    return (unsigned short)(r >> 16);
}
__device__ inline float bf16_to_f(unsigned short h) {
    return __uint_as_float((unsigned int)h << 16);
}
__device__ inline void split3(float v, unsigned short& a0, unsigned short& a1,
                              unsigned short& a2) {
    a0 = rtn_bf16(v); float r = v - bf16_to_f(a0);
    a1 = rtn_bf16(r); r -= bf16_to_f(a1);
    a2 = rtn_bf16(r);
}
__device__ inline void split2(float v, unsigned short& a0, unsigned short& a1) {
    a0 = rtn_bf16(v);
    a1 = rtn_bf16(v - bf16_to_f(a0));
}

// ---------------------------------------------------------------------------
// Prep: W1[k][n] -> 3 bf16 splits transposed [n][k]; Wc1[e][k][n] -> 2 splits.
// ---------------------------------------------------------------------------
__global__ __launch_bounds__(256)
void prep_kernel(const float* __restrict__ W1, const float* __restrict__ Wc1,
                 unsigned short* __restrict__ W1t0, unsigned short* __restrict__ W1t1,
                 unsigned short* __restrict__ W1t2,
                 unsigned short* __restrict__ Wc1t0, unsigned short* __restrict__ Wc1t1)
{
    const int idx = blockIdx.x * 256 + threadIdx.x;
    if (idx < 65536) {
        const int n = idx >> 8, k = idx & 255;
        unsigned short a0, a1, a2;
        split3(W1[k * 256 + n], a0, a1, a2);
        W1t0[idx] = a0; W1t1[idx] = a1; W1t2[idx] = a2;
    } else {
        const int j = idx - 65536;            // 0 .. 8*65536-1
        const int e = j >> 16, rem = j & 65535;
        const int n = rem >> 8, k = rem & 255;
        unsigned short a0, a1;
        split2(Wc1[(e << 16) + k * 256 + n], a0, a1);
        const int o = (e << 16) + n * 256 + k;
        Wc1t0[o] = a0; Wc1t1[o] = a1;
    }
}

// ---------------------------------------------------------------------------
// Phase A: h = relu(x@W1+b1) via 3-split/6-product bf16 MFMA (fp32-accurate);
// logits = h@W2+b2 fp32; softmax + routing; per-expert row lists.
// Pipelined: double-buffered LDS A (1 barrier/iter), B fragments prefetched
// one iteration ahead in registers, x prefetched one chunk ahead.
// ---------------------------------------------------------------------------
__global__ __launch_bounds__(512, 4)
void root_kernel(const float* __restrict__ x,
                 const unsigned short* __restrict__ Wt0,
                 const unsigned short* __restrict__ Wt1,
                 const unsigned short* __restrict__ Wt2,
                 const float* __restrict__ b1, const float* __restrict__ W2,
                 const float* __restrict__ b2, const float* __restrict__ tau,
                 float* __restrict__ out_logits, float* __restrict__ out_h,
                 float* __restrict__ out_depth, int* __restrict__ cnt,
                 int* __restrict__ lists)
{
    __shared__ unsigned short sA[2][3][64 * LDA];   // 30.7 KB double-buffered
    __shared__ float sW2[Hn * Cn];                  // 8 KB
    __shared__ float sP[64][8];                     // 2 KB
    __shared__ int   sCnt[8], sBase[8], sBest[64], sSlot[64];

    const int t    = threadIdx.x;
    const int lane = t & 63;
    const int w    = t >> 6;
    const int tx   = lane & 15;
    const int q    = lane >> 4;
    const long r0  = (long)blockIdx.x * 64;

    ((float4*)sW2)[t] = ((const float4*)W2)[t];
    if (t < 8) sCnt[t] = 0;
    ((float*)sP)[t] = 0.0f;

    const int colA = w * 32 + tx;
    const int colB = colA + 16;
    const unsigned short* bp[6] = {
        Wt0 + colA * 256 + q * 8, Wt1 + colA * 256 + q * 8, Wt2 + colA * 256 + q * 8,
        Wt0 + colB * 256 + q * 8, Wt1 + colB * 256 + q * 8, Wt2 + colB * 256 + q * 8 };

    f32x4 acc[4][2];
#pragma unroll
    for (int mt = 0; mt < 4; mt++)
#pragma unroll
        for (int nt = 0; nt < 2; nt++) acc[mt][nt] = (f32x4)0.0f;

    const int arow = t >> 3, ak4 = t & 7;
    const float4* x4 = (const float4*)x + (r0 + arow) * 64 + ak4;

    // ---- preloop: stage chunk 0 into buf 0; prefetch x chunk 1 + B frags k0=0
    float4 xv = x4[0];
    {
        unsigned short h0[4], h1[4], h2[4];
        split3(xv.x, h0[0], h1[0], h2[0]);
        split3(xv.y, h0[1], h1[1], h2[1]);
        split3(xv.z, h0[2], h1[2], h2[2]);
        split3(xv.w, h0[3], h1[3], h2[3]);
        *(ushort4*)&sA[0][0][arow * LDA + ak4 * 4] = make_ushort4(h0[0], h0[1], h0[2], h0[3]);
        *(ushort4*)&sA[0][1][arow * LDA + ak4 * 4] = make_ushort4(h1[0], h1[1], h1[2], h1[3]);
        *(ushort4*)&sA[0][2][arow * LDA + ak4 * 4] = make_ushort4(h2[0], h2[1], h2[2], h2[3]);
    }
    xv = x4[8];
    bf16x8 Bc[6];
#pragma unroll
    for (int s = 0; s < 6; s++) Bc[s] = *(const bf16x8*)(bp[s]);
    __syncthreads();

#pragma unroll 2
    for (int i = 0; i < 8; i++) {
        const int cur = i & 1;
        // stage next chunk into the alternate buffer (no barrier needed here:
        // previous reads of that buffer were separated by last iter's barrier)
        if (i < 7) {
            unsigned short h0[4], h1[4], h2[4];
            split3(xv.x, h0[0], h1[0], h2[0]);
            split3(xv.y, h0[1], h1[1], h2[1]);
            split3(xv.z, h0[2], h1[2], h2[2]);
            split3(xv.w, h0[3], h1[3], h2[3]);
            *(ushort4*)&sA[cur ^ 1][0][arow * LDA + ak4 * 4] = make_ushort4(h0[0], h0[1], h0[2], h0[3]);
            *(ushort4*)&sA[cur ^ 1][1][arow * LDA + ak4 * 4] = make_ushort4(h1[0], h1[1], h1[2], h1[3]);
            *(ushort4*)&sA[cur ^ 1][2][arow * LDA + ak4 * 4] = make_ushort4(h2[0], h2[1], h2[2], h2[3]);
            if (i < 6) xv = x4[(i + 2) * 8];
        }
        // prefetch B fragments for next iteration (latency hides under MFMA)
        bf16x8 Bnx[6];
        if (i < 7) {
            const int kn = (i + 1) * 32;
#pragma unroll
            for (int s = 0; s < 6; s++) Bnx[s] = *(const bf16x8*)(bp[s] + kn);
        }
        // compute on current buffer
#pragma unroll
        for (int mt = 0; mt < 4; mt++) {
            const bf16x8 A0 = *(const bf16x8*)&sA[cur][0][(mt * 16 + tx) * LDA + q * 8];
            const bf16x8 A1 = *(const bf16x8*)&sA[cur][1][(mt * 16 + tx) * LDA + q * 8];
            const bf16x8 A2 = *(const bf16x8*)&sA[cur][2][(mt * 16 + tx) * LDA + q * 8];
            acc[mt][0] = __builtin_amdgcn_mfma_f32_16x16x32_bf16(A0, Bc[0], acc[mt][0], 0, 0, 0);
            acc[mt][0] = __builtin_amdgcn_mfma_f32_16x16x32_bf16(A0, Bc[1], acc[mt][0], 0, 0, 0);
            acc[mt][0] = __builtin_amdgcn_mfma_f32_16x16x32_bf16(A1, Bc[0], acc[mt][0], 0, 0, 0);
            acc[mt][0] = __builtin_amdgcn_mfma_f32_16x16x32_bf16(A1, Bc[1], acc[mt][0], 0, 0, 0);
            acc[mt][0] = __builtin_amdgcn_mfma_f32_16x16x32_bf16(A0, Bc[2], acc[mt][0], 0, 0, 0);
            acc[mt][0] = __builtin_amdgcn_mfma_f32_16x16x32_bf16(A2, Bc[0], acc[mt][0], 0, 0, 0);
            acc[mt][1] = __builtin_amdgcn_mfma_f32_16x16x32_bf16(A0, Bc[3], acc[mt][1], 0, 0, 0);
            acc[mt][1] = __builtin_amdgcn_mfma_f32_16x16x32_bf16(A0, Bc[4], acc[mt][1], 0, 0, 0);
            acc[mt][1] = __builtin_amdgcn_mfma_f32_16x16x32_bf16(A1, Bc[3], acc[mt][1], 0, 0, 0);
            acc[mt][1] = __builtin_amdgcn_mfma_f32_16x16x32_bf16(A1, Bc[4], acc[mt][1], 0, 0, 0);
            acc[mt][1] = __builtin_amdgcn_mfma_f32_16x16x32_bf16(A0, Bc[5], acc[mt][1], 0, 0, 0);
            acc[mt][1] = __builtin_amdgcn_mfma_f32_16x16x32_bf16(A2, Bc[3], acc[mt][1], 0, 0, 0);
        }
        if (i < 7) {
#pragma unroll
            for (int s = 0; s < 6; s++) Bc[s] = Bnx[s];
        }
        __syncthreads();
    }

    // ---- epilogue: bias+relu, store h, fp32 head partials ----
    const float b1c0 = b1[colA], b1c1 = b1[colB];
    float w20[8], w21[8];
#pragma unroll
    for (int c = 0; c < 8; c++) { w20[c] = sW2[colA * 8 + c]; w21[c] = sW2[colB * 8 + c]; }

#pragma unroll
    for (int mt = 0; mt < 4; mt++) {
        float pm[4][8];
#pragma unroll
        for (int reg = 0; reg < 4; reg++) {
            const float h0 = fmaxf(acc[mt][0][reg] + b1c0, 0.0f);
            const float h1 = fmaxf(acc[mt][1][reg] + b1c1, 0.0f);
            const int row = mt * 16 + q * 4 + reg;
            out_h[(r0 + row) * 256 + colA] = h0;
            out_h[(r0 + row) * 256 + colB] = h1;
#pragma unroll
            for (int c = 0; c < 8; c++)
                pm[reg][c] = h0 * w20[c] + h1 * w21[c];
        }
#pragma unroll
        for (int reg = 0; reg < 4; reg++)
#pragma unroll
            for (int c = 0; c < 8; c++) {
                float v = pm[reg][c];
                v += __shfl_xor(v, 1, 16);
                v += __shfl_xor(v, 2, 16);
                v += __shfl_xor(v, 4, 16);
                v += __shfl_xor(v, 8, 16);
                if (tx == 0) atomicAdd(&sP[mt * 16 + q * 4 + reg][c], v);
            }
    }
    __syncthreads();

    // ---- routing: one thread per row ----
    if (t < 64) {
        const long row = r0 + t;
        float l[8];
        float mx = -1e30f;
#pragma unroll
        for (int c = 0; c < 8; c++) {
            l[c] = sP[t][c] + b2[c];
            mx = fmaxf(mx, l[c]);
        }
        float e[8], s = 0.0f;
#pragma unroll
        for (int c = 0; c < 8; c++) { e[c] = expf(l[c] - mx); s += e[c]; }
        const float inv = 1.0f / s;
        int best = 0; float bp2 = -1.0f;
#pragma unroll
        for (int c = 0; c < 8; c++) {
            const float pr = e[c] * inv;
            const float m  = (pr >= tau[c]) ? pr : -1.0f;
            if (m > bp2) { bp2 = m; best = c; }   // strict > == first max
        }
        const bool routed = (bp2 >= 0.0f);
        float4* lo4 = (float4*)&out_logits[row * 8];
        lo4[0] = make_float4(l[0], l[1], l[2], l[3]);
        lo4[1] = make_float4(l[4], l[5], l[6], l[7]);
        out_depth[row] = routed ? 1.0f : 0.0f;
        if (routed) {
            sSlot[t] = atomicAdd(&sCnt[best], 1);
            sBest[t] = best;
        } else {
            sBest[t] = -1;
        }
    }
    __syncthreads();
    if (t < 8) sBase[t] = sCnt[t] ? atomicAdd(&cnt[t], sCnt[t]) : 0;
    __syncthreads();
    if (t < 64 && sBest[t] >= 0) {
        const int e = sBest[t];
        lists[(long)e * Bn + sBase[e] + sSlot[t]] = (int)(r0 + t);
    }
}

// ---------------------------------------------------------------------------
// Phase B: routed rows of expert e: h_c = relu(h@Wc1[e]+bc1[e]) via
// 2-split/3-product MFMA, pipelined like root; l_c = h_c@Wc2[e]+bc2[e] fp32.
// ---------------------------------------------------------------------------
__global__ __launch_bounds__(512, 4)
void expert_kernel(const unsigned short* __restrict__ Wc1t0,
                   const unsigned short* __restrict__ Wc1t1,
                   const float* __restrict__ bc1,
                   const float* __restrict__ Wc2, const float* __restrict__ bc2,
                   float* __restrict__ out_logits, float* __restrict__ out_h,
                   const int* __restrict__ cnt, const int* __restrict__ lists)
{
    const int e = blockIdx.y;
    const int n = cnt[e];
    const int tile0 = blockIdx.x * 64;
    if (tile0 >= n) return;
    const int nrows = min(64, n - tile0);

    __shared__ unsigned short sA[2][2][64 * LDA];   // 20.5 KB
    __shared__ float sW2c[Hn * Cn];
    __shared__ float sP[64][8];
    __shared__ int   sRidx[64];

    const int t    = threadIdx.x;
    const int lane = t & 63;
    const int w    = t >> 6;
    const int tx   = lane & 15;
    const int q    = lane >> 4;

    if (t < 64) sRidx[t] = lists[(long)e * Bn + tile0 + min(t, nrows - 1)];
    ((float4*)sW2c)[t] = ((const float4*)(Wc2 + (long)e * Hn * Cn))[t];
    ((float*)sP)[t] = 0.0f;

    const unsigned short* Wh = Wc1t0 + (long)e * 65536;
    const unsigned short* Wl = Wc1t1 + (long)e * 65536;
    const int colA = w * 32 + tx;
    const int colB = colA + 16;
    const unsigned short* bp[4] = {
        Wh + colA * 256 + q * 8, Wl + colA * 256 + q * 8,
        Wh + colB * 256 + q * 8, Wl + colB * 256 + q * 8 };

    f32x4 acc[4][2];
#pragma unroll
    for (int mt = 0; mt < 4; mt++)
#pragma unroll
        for (int nt = 0; nt < 2; nt++) acc[mt][nt] = (f32x4)0.0f;

    const int arow = t >> 3, ak4 = t & 7;
    __syncthreads();   // sRidx visible
    const float4* h4 = (const float4*)out_h + (long)sRidx[arow] * 64 + ak4;

    float4 xv = h4[0];
    {
        unsigned short h0[4], h1[4];
        split2(xv.x, h0[0], h1[0]);
        split2(xv.y, h0[1], h1[1]);
        split2(xv.z, h0[2], h1[2]);
        split2(xv.w, h0[3], h1[3]);
        *(ushort4*)&sA[0][0][arow * LDA + ak4 * 4] = make_ushort4(h0[0], h0[1], h0[2], h0[3]);
        *(ushort4*)&sA[0][1][arow * LDA + ak4 * 4] = make_ushort4(h1[0], h1[1], h1[2], h1[3]);
    }
    xv = h4[8];
    bf16x8 Bc[4];
#pragma unroll
    for (int s = 0; s < 4; s++) Bc[s] = *(const bf16x8*)(bp[s]);
    __syncthreads();

#pragma unroll 2
    for (int i = 0; i < 8; i++) {
        const int cur = i & 1;
        if (i < 7) {
            unsigned short h0[4], h1[4];
            split2(xv.x, h0[0], h1[0]);
            split2(xv.y, h0[1], h1[1]);
            split2(xv.z, h0[2], h1[2]);
            split2(xv.w, h0[3], h1[3]);
            *(ushort4*)&sA[cur ^ 1][0][arow * LDA + ak4 * 4] = make_ushort4(h0[0], h0[1], h0[2], h0[3]);
            *(ushort4*)&sA[cur ^ 1][1][arow * LDA + ak4 * 4] = make_ushort4(h1[0], h1[1], h1[2], h1[3]);
            if (i < 6) xv = h4[(i + 2) * 8];
        }
        bf16x8 Bnx[4];
        if (i < 7) {
            const int kn = (i + 1) * 32;
#pragma unroll
            for (int s = 0; s < 4; s++) Bnx[s] = *(const bf16x8*)(bp[s] + kn);
        }
#pragma unroll
        for (int mt = 0; mt < 4; mt++) {
            const bf16x8 A0 = *(const bf16x8*)&sA[cur][0][(mt * 16 + tx) * LDA + q * 8];
            const bf16x8 A1 = *(const bf16x8*)&sA[cur][1][(mt * 16 + tx) * LDA + q * 8];
            acc[mt][0] = __builtin_amdgcn_mfma_f32_16x16x32_bf16(A0, Bc[0], acc[mt][0], 0, 0, 0);
            acc[mt][0] = __builtin_amdgcn_mfma_f32_16x16x32_bf16(A0, Bc[1], acc[mt][0], 0, 0, 0);
            acc[mt][0] = __builtin_amdgcn_mfma_f32_16x16x32_bf16(A1, Bc[0], acc[mt][0], 0, 0, 0);
            acc[mt][1] = __builtin_amdgcn_mfma_f32_16x16x32_bf16(A0, Bc[2], acc[mt][1], 0, 0, 0);
            acc[mt][1] = __builtin_amdgcn_mfma_f32_16x16x32_bf16(A0, Bc[3], acc[mt][1], 0, 0, 0);
            acc[mt][1] = __builtin_amdgcn_mfma_f32_16x16x32_bf16(A1, Bc[2], acc[mt][1], 0, 0, 0);
        }
        if (i < 7) {
#pragma unroll
            for (int s = 0; s < 4; s++) Bc[s] = Bnx[s];
        }
        __syncthreads();
    }

    const float* bc1e = bc1 + (long)e * Hn;
    const float b1c0 = bc1e[colA], b1c1 = bc1e[colB];
    float w20[8], w21[8];
#pragma unroll
    for (int c = 0; c < 8; c++) { w20[c] = sW2c[colA * 8 + c]; w21[c] = sW2c[colB * 8 + c]; }

#pragma unroll
    for (int mt = 0; mt < 4; mt++) {
        float pm[4][8];
#pragma unroll
        for (int reg = 0; reg < 4; reg++) {
            const float h0 = fmaxf(acc[mt][0][reg] + b1c0, 0.0f);
            const float h1 = fmaxf(acc[mt][1][reg] + b1c1, 0.0f);
            const int row = mt * 16 + q * 4 + reg;
            if (row < nrows) {
                out_h[(long)sRidx[row] * 256 + colA] = h0;
                out_h[(long)sRidx[row] * 256 + colB] = h1;
            }
#pragma unroll
            for (int c = 0; c < 8; c++)
                pm[reg][c] = h0 * w20[c] + h1 * w21[c];
        }
#pragma unroll
        for (int reg = 0; reg < 4; reg++)
#pragma unroll
            for (int c = 0; c < 8; c++) {
                float v = pm[reg][c];
                v += __shfl_xor(v, 1, 16);
                v += __shfl_xor(v, 2, 16);
                v += __shfl_xor(v, 4, 16);
                v += __shfl_xor(v, 8, 16);
                if (tx == 0) atomicAdd(&sP[mt * 16 + q * 4 + reg][c], v);
            }
    }
    __syncthreads();

    if (t < nrows) {
        const long row = sRidx[t];
        const float* bc2e = bc2 + (long)e * Cn;
        float4* lo4 = (float4*)&out_logits[row * 8];
        lo4[0] = make_float4(sP[t][0] + bc2e[0], sP[t][1] + bc2e[1],
                             sP[t][2] + bc2e[2], sP[t][3] + bc2e[3]);
        lo4[1] = make_float4(sP[t][4] + bc2e[4], sP[t][5] + bc2e[5],
                             sP[t][6] + bc2e[6], sP[t][7] + bc2e[7]);
    }
}

extern "C" void kernel_launch(void* const* d_in, const int* in_sizes, int n_in,
                              void* d_out, int out_size, void* d_ws, size_t ws_size,
                              hipStream_t stream)
{
    const float* x   = (const float*)d_in[0];
    const float* W1  = (const float*)d_in[1];
    const float* b1  = (const float*)d_in[2];
    const float* W2  = (const float*)d_in[3];
    const float* b2  = (const float*)d_in[4];
    const float* Wc1 = (const float*)d_in[5];
    const float* bc1 = (const float*)d_in[6];
    const float* Wc2 = (const float*)d_in[7];
    const float* bc2 = (const float*)d_in[8];
    const float* tau = (const float*)d_in[9];

    float* out_logits = (float*)d_out;                       // [B, 8]
    float* out_h      = out_logits + (long)Bn * Cn;          // [B, 256]
    float* out_depth  = out_h + (long)Bn * Hn;               // [B]

    char* wsb = (char*)d_ws;
    int* cnt   = (int*)wsb;                                  // 8 counters
    int* lists = (int*)(wsb + 128);                          // 8 x B ints (4MB)
    unsigned short* W1t0  = (unsigned short*)(wsb + 128 + (size_t)8 * Bn * 4);
    unsigned short* W1t1  = W1t0 + 65536;
    unsigned short* W1t2  = W1t1 + 65536;
    unsigned short* Wc1t0 = W1t2 + 65536;
    unsigned short* Wc1t1 = Wc1t0 + 8 * 65536;

    hipMemsetAsync(d_ws, 0, 128, stream);

    prep_kernel<<<dim3((65536 + 8 * 65536) / 256), 256, 0, stream>>>(
        W1, Wc1, W1t0, W1t1, W1t2, Wc1t0, Wc1t1);

    root_kernel<<<dim3(Bn / 64), 512, 0, stream>>>(
        x, W1t0, W1t1, W1t2, b1, W2, b2, tau, out_logits, out_h, out_depth,
        cnt, lists);

    expert_kernel<<<dim3(Bn / 64, 8), 512, 0, stream>>>(
        Wc1t0, Wc1t1, bc1, Wc2, bc2, out_logits, out_h, cnt, lists);
}

// Round 5
// 615.888 us; speedup vs baseline: 1.2514x; 1.0676x over previous
//
#include <hip/hip_runtime.h>

// Problem constants
#define Bn 131072
#define Dn 256
#define Hn 256
#define Cn 8

typedef __attribute__((ext_vector_type(4))) float f32x4;
typedef __attribute__((ext_vector_type(8))) __bf16 bf16x8;

#define LDA 40   // LDS row stride in bf16 units (80B): <=2-way bank aliasing = free

// ---- bf16 helpers (round-to-nearest-even) ----
__device__ inline unsigned short rtn_bf16(float v) {
    unsigned int u = __float_as_uint(v);
    unsigned int r = u + 0x7fffu + ((u >> 16) & 1u);
    return (unsigned short)(r >> 16);
}
__device__ inline float bf16_to_f(unsigned short h) {
    return __uint_as_float((unsigned int)h << 16);
}
__device__ inline void split3(float v, unsigned short& a0, unsigned short& a1,
                              unsigned short& a2) {
    a0 = rtn_bf16(v); float r = v - bf16_to_f(a0);
    a1 = rtn_bf16(r); r -= bf16_to_f(a1);
    a2 = rtn_bf16(r);
}
__device__ inline ushort4 cvt4(float4 v) {
    return make_ushort4(rtn_bf16(v.x), rtn_bf16(v.y), rtn_bf16(v.z), rtn_bf16(v.w));
}

// ---------------------------------------------------------------------------
// Prep: W1[k][n] -> 3 bf16 splits transposed [n][k] (routing-accurate path);
//       Wc1[e][k][n] -> single bf16 transposed [e][n][k] (value-accurate path).
// ---------------------------------------------------------------------------
__global__ __launch_bounds__(256)
void prep_kernel(const float* __restrict__ W1, const float* __restrict__ Wc1,
                 unsigned short* __restrict__ W1t0, unsigned short* __restrict__ W1t1,
                 unsigned short* __restrict__ W1t2, unsigned short* __restrict__ Wc1t)
{
    const int idx = blockIdx.x * 256 + threadIdx.x;
    if (idx < 65536) {
        const int n = idx >> 8, k = idx & 255;
        unsigned short a0, a1, a2;
        split3(W1[k * 256 + n], a0, a1, a2);
        W1t0[idx] = a0; W1t1[idx] = a1; W1t2[idx] = a2;
    } else {
        const int j = idx - 65536;            // 0 .. 8*65536-1
        const int e = j >> 16, rem = j & 65535;
        const int n = rem >> 8, k = rem & 255;
        Wc1t[(e << 16) + n * 256 + k] = rtn_bf16(Wc1[(e << 16) + k * 256 + n]);
    }
}

// ---------------------------------------------------------------------------
// Phase A: h = relu(x@W1+b1) via 3-split/6-product bf16 MFMA (fp32-accurate,
// needed for the tau-threshold routing); logits = h@W2+b2 fp32; routing.
// Block: 512 threads (8 waves), tile = 128 rows x 256 cols; wave w owns cols
// [w*32, w*32+32) as 2 n-tiles; 8 m-tiles of 16. Single-buffer LDS A.
// ---------------------------------------------------------------------------
__global__ __launch_bounds__(512, 4)
void root_kernel(const float* __restrict__ x,
                 const unsigned short* __restrict__ Wt0,
                 const unsigned short* __restrict__ Wt1,
                 const unsigned short* __restrict__ Wt2,
                 const float* __restrict__ b1, const float* __restrict__ W2,
                 const float* __restrict__ b2, const float* __restrict__ tau,
                 float* __restrict__ out_logits, float* __restrict__ out_h,
                 float* __restrict__ out_depth, int* __restrict__ cnt,
                 int* __restrict__ lists)
{
    __shared__ unsigned short sA0[128 * LDA], sA1[128 * LDA], sA2[128 * LDA]; // 30 KB
    __shared__ float sP[128][8];                                              // 4 KB
    __shared__ int   sCnt[8], sBase[8], sBest[128], sSlot[128];

    const int t    = threadIdx.x;
    const int lane = t & 63;
    const int w    = t >> 6;
    const int tx   = lane & 15;
    const int q    = lane >> 4;
    const long r0  = (long)blockIdx.x * 128;

    if (t < 8) sCnt[t] = 0;
    ((float*)sP)[t] = 0.0f;
    ((float*)sP)[t + 512] = 0.0f;

    const int colA = w * 32 + tx;
    const int colB = colA + 16;
    const unsigned short* bp0 = Wt0 + colA * 256 + q * 8;
    const unsigned short* bp1 = Wt1 + colA * 256 + q * 8;
    const unsigned short* bp2 = Wt2 + colA * 256 + q * 8;
    const unsigned short* bp3 = Wt0 + colB * 256 + q * 8;
    const unsigned short* bp4 = Wt1 + colB * 256 + q * 8;
    const unsigned short* bp5 = Wt2 + colB * 256 + q * 8;

    f32x4 acc[8][2];
#pragma unroll
    for (int mt = 0; mt < 8; mt++)
#pragma unroll
        for (int nt = 0; nt < 2; nt++) acc[mt][nt] = (f32x4)0.0f;

    // staging map: thread t covers rows ar and ar+64 at float4-slot ak
    const int ar = t >> 3, ak = t & 7;
    const float4* xr0 = (const float4*)x + (r0 + ar) * 64 + ak;
    const float4* xr1 = (const float4*)x + (r0 + 64 + ar) * 64 + ak;
    float4 xv0 = xr0[0];
    float4 xv1 = xr1[0];

    for (int i = 0; i < 8; i++) {
        if (i) __syncthreads();             // previous iter's reads complete
        {
            unsigned short h0[4], h1[4], h2[4];
            split3(xv0.x, h0[0], h1[0], h2[0]);
            split3(xv0.y, h0[1], h1[1], h2[1]);
            split3(xv0.z, h0[2], h1[2], h2[2]);
            split3(xv0.w, h0[3], h1[3], h2[3]);
            *(ushort4*)&sA0[ar * LDA + ak * 4] = make_ushort4(h0[0], h0[1], h0[2], h0[3]);
            *(ushort4*)&sA1[ar * LDA + ak * 4] = make_ushort4(h1[0], h1[1], h1[2], h1[3]);
            *(ushort4*)&sA2[ar * LDA + ak * 4] = make_ushort4(h2[0], h2[1], h2[2], h2[3]);
            split3(xv1.x, h0[0], h1[0], h2[0]);
            split3(xv1.y, h0[1], h1[1], h2[1]);
            split3(xv1.z, h0[2], h1[2], h2[2]);
            split3(xv1.w, h0[3], h1[3], h2[3]);
            *(ushort4*)&sA0[(64 + ar) * LDA + ak * 4] = make_ushort4(h0[0], h0[1], h0[2], h0[3]);
            *(ushort4*)&sA1[(64 + ar) * LDA + ak * 4] = make_ushort4(h1[0], h1[1], h1[2], h1[3]);
            *(ushort4*)&sA2[(64 + ar) * LDA + ak * 4] = make_ushort4(h2[0], h2[1], h2[2], h2[3]);
        }
        if (i < 7) { xv0 = xr0[(i + 1) * 8]; xv1 = xr1[(i + 1) * 8]; }
        __syncthreads();

        const int ko = i * 32;
        const bf16x8 B0 = *(const bf16x8*)(bp0 + ko);
        const bf16x8 B1 = *(const bf16x8*)(bp1 + ko);
        const bf16x8 B2 = *(const bf16x8*)(bp2 + ko);
        const bf16x8 B3 = *(const bf16x8*)(bp3 + ko);
        const bf16x8 B4 = *(const bf16x8*)(bp4 + ko);
        const bf16x8 B5 = *(const bf16x8*)(bp5 + ko);

#pragma unroll
        for (int mt = 0; mt < 8; mt++) {
            const bf16x8 A0 = *(const bf16x8*)&sA0[(mt * 16 + tx) * LDA + q * 8];
            const bf16x8 A1 = *(const bf16x8*)&sA1[(mt * 16 + tx) * LDA + q * 8];
            const bf16x8 A2 = *(const bf16x8*)&sA2[(mt * 16 + tx) * LDA + q * 8];
            acc[mt][0] = __builtin_amdgcn_mfma_f32_16x16x32_bf16(A0, B0, acc[mt][0], 0, 0, 0);
            acc[mt][0] = __builtin_amdgcn_mfma_f32_16x16x32_bf16(A0, B1, acc[mt][0], 0, 0, 0);
            acc[mt][0] = __builtin_amdgcn_mfma_f32_16x16x32_bf16(A1, B0, acc[mt][0], 0, 0, 0);
            acc[mt][0] = __builtin_amdgcn_mfma_f32_16x16x32_bf16(A1, B1, acc[mt][0], 0, 0, 0);
            acc[mt][0] = __builtin_amdgcn_mfma_f32_16x16x32_bf16(A0, B2, acc[mt][0], 0, 0, 0);
            acc[mt][0] = __builtin_amdgcn_mfma_f32_16x16x32_bf16(A2, B0, acc[mt][0], 0, 0, 0);
            acc[mt][1] = __builtin_amdgcn_mfma_f32_16x16x32_bf16(A0, B3, acc[mt][1], 0, 0, 0);
            acc[mt][1] = __builtin_amdgcn_mfma_f32_16x16x32_bf16(A0, B4, acc[mt][1], 0, 0, 0);
            acc[mt][1] = __builtin_amdgcn_mfma_f32_16x16x32_bf16(A1, B3, acc[mt][1], 0, 0, 0);
            acc[mt][1] = __builtin_amdgcn_mfma_f32_16x16x32_bf16(A1, B4, acc[mt][1], 0, 0, 0);
            acc[mt][1] = __builtin_amdgcn_mfma_f32_16x16x32_bf16(A0, B5, acc[mt][1], 0, 0, 0);
            acc[mt][1] = __builtin_amdgcn_mfma_f32_16x16x32_bf16(A2, B3, acc[mt][1], 0, 0, 0);
        }
    }

    // ---- epilogue: bias+relu, store h, fp32 head partials ----
    const float b1c0 = b1[colA], b1c1 = b1[colB];
    float w20[8], w21[8];
    {
        const float4 a0 = ((const float4*)W2)[colA * 2];
        const float4 a1 = ((const float4*)W2)[colA * 2 + 1];
        const float4 c0 = ((const float4*)W2)[colB * 2];
        const float4 c1 = ((const float4*)W2)[colB * 2 + 1];
        w20[0]=a0.x; w20[1]=a0.y; w20[2]=a0.z; w20[3]=a0.w;
        w20[4]=a1.x; w20[5]=a1.y; w20[6]=a1.z; w20[7]=a1.w;
        w21[0]=c0.x; w21[1]=c0.y; w21[2]=c0.z; w21[3]=c0.w;
        w21[4]=c1.x; w21[5]=c1.y; w21[6]=c1.z; w21[7]=c1.w;
    }

#pragma unroll
    for (int mt = 0; mt < 8; mt++) {
        float pm[4][8];
#pragma unroll
        for (int reg = 0; reg < 4; reg++) {
            const float h0 = fmaxf(acc[mt][0][reg] + b1c0, 0.0f);
            const float h1 = fmaxf(acc[mt][1][reg] + b1c1, 0.0f);
            const int row = mt * 16 + q * 4 + reg;
            out_h[(r0 + row) * 256 + colA] = h0;
            out_h[(r0 + row) * 256 + colB] = h1;
#pragma unroll
            for (int c = 0; c < 8; c++)
                pm[reg][c] = h0 * w20[c] + h1 * w21[c];
        }
#pragma unroll
        for (int reg = 0; reg < 4; reg++)
#pragma unroll
            for (int c = 0; c < 8; c++) {
                float v = pm[reg][c];
                v += __shfl_xor(v, 1, 16);
                v += __shfl_xor(v, 2, 16);
                v += __shfl_xor(v, 4, 16);
                v += __shfl_xor(v, 8, 16);
                if (tx == 0) atomicAdd(&sP[mt * 16 + q * 4 + reg][c], v);
            }
    }
    __syncthreads();

    // ---- routing: one thread per row ----
    if (t < 128) {
        const long row = r0 + t;
        float l[8];
        float mx = -1e30f;
#pragma unroll
        for (int c = 0; c < 8; c++) {
            l[c] = sP[t][c] + b2[c];
            mx = fmaxf(mx, l[c]);
        }
        float e[8], s = 0.0f;
#pragma unroll
        for (int c = 0; c < 8; c++) { e[c] = expf(l[c] - mx); s += e[c]; }
        const float inv = 1.0f / s;
        int best = 0; float bp = -1.0f;
#pragma unroll
        for (int c = 0; c < 8; c++) {
            const float pr = e[c] * inv;
            const float m  = (pr >= tau[c]) ? pr : -1.0f;
            if (m > bp) { bp = m; best = c; }   // strict > == first max (jnp.argmax)
        }
        const bool routed = (bp >= 0.0f);
        float4* lo4 = (float4*)&out_logits[row * 8];
        lo4[0] = make_float4(l[0], l[1], l[2], l[3]);
        lo4[1] = make_float4(l[4], l[5], l[6], l[7]);
        out_depth[row] = routed ? 1.0f : 0.0f;
        if (routed) {
            sSlot[t] = atomicAdd(&sCnt[best], 1);
            sBest[t] = best;
        } else {
            sBest[t] = -1;
        }
    }
    __syncthreads();
    if (t < 8) sBase[t] = sCnt[t] ? atomicAdd(&cnt[t], sCnt[t]) : 0;
    __syncthreads();
    if (t < 128 && sBest[t] >= 0) {
        const int e = sBest[t];
        lists[(long)e * Bn + sBase[e] + sSlot[t]] = (int)(r0 + t);
    }
}

// ---------------------------------------------------------------------------
// Phase B: routed rows of expert e: h_c = relu(h@Wc1[e]+bc1[e]) in PLAIN bf16
// (error ~4e-3 << 8.4e-2 threshold; routing already fixed by root);
// l_c = h_c@Wc2[e]+bc2[e] fp32. Tile = 128 rows, double-buffered LDS A.
// ---------------------------------------------------------------------------
__global__ __launch_bounds__(512, 4)
void expert_kernel(const unsigned short* __restrict__ Wc1t,
                   const float* __restrict__ bc1,
                   const float* __restrict__ Wc2, const float* __restrict__ bc2,
                   float* __restrict__ out_logits, float* __restrict__ out_h,
                   const int* __restrict__ cnt, const int* __restrict__ lists)
{
    const int e = blockIdx.y;
    const int n = cnt[e];
    const int tile0 = blockIdx.x * 128;
    if (tile0 >= n) return;
    const int nrows = min(128, n - tile0);

    __shared__ unsigned short sA[2][128 * LDA];   // 20.5 KB
    __shared__ float sP[128][8];                  // 4 KB
    __shared__ int   sRidx[128];

    const int t    = threadIdx.x;
    const int lane = t & 63;
    const int w    = t >> 6;
    const int tx   = lane & 15;
    const int q    = lane >> 4;

    if (t < 128) sRidx[t] = lists[(long)e * Bn + tile0 + min(t, nrows - 1)];
    ((float*)sP)[t] = 0.0f;
    ((float*)sP)[t + 512] = 0.0f;

    const unsigned short* W = Wc1t + (long)e * 65536;
    const int colA = w * 32 + tx;
    const int colB = colA + 16;
    const unsigned short* bpA = W + colA * 256 + q * 8;
    const unsigned short* bpB = W + colB * 256 + q * 8;

    f32x4 acc[8][2];
#pragma unroll
    for (int mt = 0; mt < 8; mt++)
#pragma unroll
        for (int nt = 0; nt < 2; nt++) acc[mt][nt] = (f32x4)0.0f;

    const int ar = t >> 3, ak = t & 7;
    __syncthreads();   // sRidx visible
    const float4* hr0 = (const float4*)out_h + (long)sRidx[ar] * 64 + ak;
    const float4* hr1 = (const float4*)out_h + (long)sRidx[64 + ar] * 64 + ak;

    float4 xv0 = hr0[0], xv1 = hr1[0];
    *(ushort4*)&sA[0][ar * LDA + ak * 4]        = cvt4(xv0);
    *(ushort4*)&sA[0][(64 + ar) * LDA + ak * 4] = cvt4(xv1);
    xv0 = hr0[8]; xv1 = hr1[8];
    bf16x8 BcA = *(const bf16x8*)(bpA);
    bf16x8 BcB = *(const bf16x8*)(bpB);
    __syncthreads();

#pragma unroll 2
    for (int i = 0; i < 8; i++) {
        const int cur = i & 1;
        if (i < 7) {
            *(ushort4*)&sA[cur ^ 1][ar * LDA + ak * 4]        = cvt4(xv0);
            *(ushort4*)&sA[cur ^ 1][(64 + ar) * LDA + ak * 4] = cvt4(xv1);
            if (i < 6) { xv0 = hr0[(i + 2) * 8]; xv1 = hr1[(i + 2) * 8]; }
        }
        bf16x8 BnA, BnB;
        if (i < 7) {
            BnA = *(const bf16x8*)(bpA + (i + 1) * 32);
            BnB = *(const bf16x8*)(bpB + (i + 1) * 32);
        }
#pragma unroll
        for (int mt = 0; mt < 8; mt++) {
            const bf16x8 A = *(const bf16x8*)&sA[cur][(mt * 16 + tx) * LDA + q * 8];
            acc[mt][0] = __builtin_amdgcn_mfma_f32_16x16x32_bf16(A, BcA, acc[mt][0], 0, 0, 0);
            acc[mt][1] = __builtin_amdgcn_mfma_f32_16x16x32_bf16(A, BcB, acc[mt][1], 0, 0, 0);
        }
        if (i < 7) { BcA = BnA; BcB = BnB; }
        __syncthreads();
    }

    // ---- epilogue ----
    const float* bc1e = bc1 + (long)e * Hn;
    const float b1c0 = bc1e[colA], b1c1 = bc1e[colB];
    const float* W2c = Wc2 + (long)e * Hn * Cn;
    float w20[8], w21[8];
    {
        const float4 a0 = ((const float4*)W2c)[colA * 2];
        const float4 a1 = ((const float4*)W2c)[colA * 2 + 1];
        const float4 c0 = ((const float4*)W2c)[colB * 2];
        const float4 c1 = ((const float4*)W2c)[colB * 2 + 1];
        w20[0]=a0.x; w20[1]=a0.y; w20[2]=a0.z; w20[3]=a0.w;
        w20[4]=a1.x; w20[5]=a1.y; w20[6]=a1.z; w20[7]=a1.w;
        w21[0]=c0.x; w21[1]=c0.y; w21[2]=c0.z; w21[3]=c0.w;
        w21[4]=c1.x; w21[5]=c1.y; w21[6]=c1.z; w21[7]=c1.w;
    }

#pragma unroll
    for (int mt = 0; mt < 8; mt++) {
        float pm[4][8];
#pragma unroll
        for (int reg = 0; reg < 4; reg++) {
            const float h0 = fmaxf(acc[mt][0][reg] + b1c0, 0.0f);
            const float h1 = fmaxf(acc[mt][1][reg] + b1c1, 0.0f);
            const int row = mt * 16 + q * 4 + reg;
            if (row < nrows) {
                out_h[(long)sRidx[row] * 256 + colA] = h0;
                out_h[(long)sRidx[row] * 256 + colB] = h1;
            }
#pragma unroll
            for (int c = 0; c < 8; c++)
                pm[reg][c] = h0 * w20[c] + h1 * w21[c];
        }
#pragma unroll
        for (int reg = 0; reg < 4; reg++)
#pragma unroll
            for (int c = 0; c < 8; c++) {
                float v = pm[reg][c];
                v += __shfl_xor(v, 1, 16);
                v += __shfl_xor(v, 2, 16);
                v += __shfl_xor(v, 4, 16);
                v += __shfl_xor(v, 8, 16);
                if (tx == 0) atomicAdd(&sP[mt * 16 + q * 4 + reg][c], v);
            }
    }
    __syncthreads();

    if (t < nrows) {
        const long row = sRidx[t];
        const float* bc2e = bc2 + (long)e * Cn;
        float4* lo4 = (float4*)&out_logits[row * 8];
        lo4[0] = make_float4(sP[t][0] + bc2e[0], sP[t][1] + bc2e[1],
                             sP[t][2] + bc2e[2], sP[t][3] + bc2e[3]);
        lo4[1] = make_float4(sP[t][4] + bc2e[4], sP[t][5] + bc2e[5],
                             sP[t][6] + bc2e[6], sP[t][7] + bc2e[7]);
    }
}

extern "C" void kernel_launch(void* const* d_in, const int* in_sizes, int n_in,
                              void* d_out, int out_size, void* d_ws, size_t ws_size,
                              hipStream_t stream)
{
    const float* x   = (const float*)d_in[0];
    const float* W1  = (const float*)d_in[1];
    const float* b1  = (const float*)d_in[2];
    const float* W2  = (const float*)d_in[3];
    const float* b2  = (const float*)d_in[4];
    const float* Wc1 = (const float*)d_in[5];
    const float* bc1 = (const float*)d_in[6];
    const float* Wc2 = (const float*)d_in[7];
    const float* bc2 = (const float*)d_in[8];
    const float* tau = (const float*)d_in[9];

    float* out_logits = (float*)d_out;                       // [B, 8]
    float* out_h      = out_logits + (long)Bn * Cn;          // [B, 256]
    float* out_depth  = out_h + (long)Bn * Hn;               // [B]

    char* wsb = (char*)d_ws;
    int* cnt   = (int*)wsb;                                  // 8 counters
    int* lists = (int*)(wsb + 128);                          // 8 x B ints (4MB)
    unsigned short* W1t0 = (unsigned short*)(wsb + 128 + (size_t)8 * Bn * 4);
    unsigned short* W1t1 = W1t0 + 65536;
    unsigned short* W1t2 = W1t1 + 65536;
    unsigned short* Wc1t = W1t2 + 65536;                     // 8 x 65536 bf16

    hipMemsetAsync(d_ws, 0, 128, stream);

    prep_kernel<<<dim3((65536 + 8 * 65536) / 256), 256, 0, stream>>>(
        W1, Wc1, W1t0, W1t1, W1t2, Wc1t);

    root_kernel<<<dim3(Bn / 128), 512, 0, stream>>>(
        x, W1t0, W1t1, W1t2, b1, W2, b2, tau, out_logits, out_h, out_depth,
        cnt, lists);

    expert_kernel<<<dim3(Bn / 128, 8), 512, 0, stream>>>(
        Wc1t, bc1, Wc2, bc2, out_logits, out_h, cnt, lists);
}